// Round 8
// baseline (253.283 us; speedup 1.0000x reference)
//
#include <hip/hip_runtime.h>
#include <hip/hip_cooperative_groups.h>

namespace cg = cooperative_groups;

typedef __attribute__((ext_vector_type(4))) float f32x4;
typedef __attribute__((ext_vector_type(8))) short bf16x8;
typedef long fp8x8;   // 8 packed e4m3 bytes (i64 MFMA operand)

#define NH 4

// round-to-nearest-even f32 -> bf16
static __device__ __forceinline__ unsigned short f2bf(float f){
  unsigned u = __float_as_uint(f);
  u += 0x7FFFu + ((u >> 16) & 1u);
  return (unsigned short)(u >> 16);
}

// pack two f32 -> two bf16 (round-half-up) in one uint (low = a)
static __device__ __forceinline__ unsigned pack2bf(float a, float b){
  return __builtin_amdgcn_perm(__float_as_uint(b) + 0x8000u,
                               __float_as_uint(a) + 0x8000u, 0x07060302u);
}

// pack two f32 -> two bf16 TRUNCATING (1 v_perm). Used only for P: the same
// truncated P feeds both O=P*V and l=P*1, so the truncation bias cancels.
static __device__ __forceinline__ unsigned pack2bf_t(float a, float b){
  return __builtin_amdgcn_perm(__float_as_uint(b), __float_as_uint(a), 0x07060302u);
}

// pack 4 floats into 4 fp8(e4m3) bytes of one int (byte0 = a)
static __device__ __forceinline__ int pack_fp8x4(float a, float b, float c, float d){
  int w = __builtin_amdgcn_cvt_pk_fp8_f32(a, b, 0, false);
  w     = __builtin_amdgcn_cvt_pk_fp8_f32(c, d, w, true);
  return w;
}

// ---- shared attn inner-loop macros (used by fused kernel and fallback) ----
// one i-tile granule: 4 QK MFMAs -> 8 exp2 -> 4 packs -> 2 PV MFMAs.
#define ITILE(QA, QB, OO, LL)                                                 \
  {                                                                           \
    f32x4 s = __builtin_amdgcn_mfma_f32_16x16x32_fp8_fp8(a0, QA, z, 0,0,0);   \
    s = __builtin_amdgcn_mfma_f32_16x16x32_fp8_fp8(a1, QB, s, 0,0,0);         \
    f32x4 u = __builtin_amdgcn_mfma_f32_16x16x32_fp8_fp8(b0, QA, z, 0,0,0);   \
    u = __builtin_amdgcn_mfma_f32_16x16x32_fp8_fp8(b1, QB, u, 0,0,0);         \
    float e0 = __builtin_amdgcn_exp2f(s[0]);                                  \
    float e1 = __builtin_amdgcn_exp2f(s[1]);                                  \
    float e2 = __builtin_amdgcn_exp2f(s[2]);                                  \
    float e3 = __builtin_amdgcn_exp2f(s[3]);                                  \
    float f0 = __builtin_amdgcn_exp2f(u[0]);                                  \
    float f1 = __builtin_amdgcn_exp2f(u[1]);                                  \
    float f2 = __builtin_amdgcn_exp2f(u[2]);                                  \
    float f3 = __builtin_amdgcn_exp2f(u[3]);                                  \
    union { uint4 uu; bf16x8 v; } pq;                                         \
    pq.uu = make_uint4(pack2bf_t(e0,e1), pack2bf_t(e2,e3),                    \
                       pack2bf_t(f0,f1), pack2bf_t(f2,f3));                   \
    OO = __builtin_amdgcn_mfma_f32_16x16x32_bf16(pq.v, vfv,   OO, 0,0,0);     \
    LL = __builtin_amdgcn_mfma_f32_16x16x32_bf16(pq.v, vones, LL, 0,0,0);     \
  }

#define ATTN_CHUNK(KA, KB, VV)                                                \
  {                                                                           \
    const fp8x8 a0 = (fp8x8)KA.x, a1 = (fp8x8)KA.y;                           \
    const fp8x8 b0 = (fp8x8)KB.x, b1 = (fp8x8)KB.y;                           \
    union { uint4 uu; bf16x8 v; } vfu; vfu.uu = VV;                           \
    const bf16x8 vfv = vfu.v;                                                 \
    ITILE(qf00, qf01, o0, la0)                                                \
    ITILE(qf10, qf11, o1, la1)                                                \
    ITILE(qf20, qf21, o2, la2)                                                \
    ITILE(qf30, qf31, o3, la3)                                                \
  }

// R19-proven SGB: the 2-chunk body has 48 MFMA (24/chunk: 16 QK + 4 PV +
// 4 la) and ~120 VALU/trans. 16 x {3 MFMA, 6 VALU} = 48:96 covers it.
// (R22's 12x{2,8} was a miscount -- covered only half the body, +0.8us.)
#define ATTN_SGB                                                              \
    _Pragma("unroll")                                                         \
    for (int g = 0; g < 16; ++g){                                             \
      __builtin_amdgcn_sched_group_barrier(0x008, 3, 0);                      \
      __builtin_amdgcn_sched_group_barrier(0x002, 6, 0);                      \
    }

// =========================================================================
// R23: SINGLE COOPERATIVE KERNEL. The ~70us gap between dur_us (118) and
// attn (45) is CONSTANT across all rounds -- including R20 where attn was
// 6.5x longer (363.8 - 290 = 74) -- i.e. it is per-launch/serialization
// overhead of the 3-kernel pipeline, not compute (proj+wprep are worth
// <= 5-7us by roofline). Fusing to ONE launch attacks the largest
// remaining line item. Each block: local weight-prep (W is 64KB total,
// L2-resident; redundancy free) -> proj of its own 64 rows (Qfr is
// block-local; Kt/Vt global) -> grid.sync (Kt/Vt cross-block visibility)
// -> attn phase verbatim R19 (best verified: 44.4us) with SGB 16x{3,6}.
// LDS: prep (20.7KB) and xf (8KB) alias the 59KB part[] phase-sequentially.
// 512 blocks = exactly 2/CU (LDS) -> cooperative co-residency OK;
// __launch_bounds__(512,4) caps VGPR at 128 (R20 lesson: don't strangle).
// =========================================================================
__global__ __launch_bounds__(512, 4) void fused_kernel(
    const float* __restrict__ x,
    const float* __restrict__ Wq, const float* __restrict__ bq,
    const float* __restrict__ Wk, const float* __restrict__ bk,
    const float* __restrict__ Wv, const float* __restrict__ bv,
    unsigned char* __restrict__ Qfr, unsigned char* __restrict__ Kt,
    unsigned short* __restrict__ Vt, float* __restrict__ out, int n)
{
  __shared__ float part[7][64][33];       // 59,136 B; aliased by prep buffers
  __shared__ float bql[64], bkl[64], bvl[16];

  unsigned short* wqT = (unsigned short*)&part[0][0][0];  // [64][72]
  unsigned short* wkT = wqT + 64*72;
  unsigned short* wvT = wkT + 64*72;                      // 20,736 B total
  unsigned short* xf  = (unsigned short*)&part[0][0][0];  // 8,192 B (phase C)

  const int t    = threadIdx.x;
  const int lane = t & 63;
  const int w    = t >> 6;                // 0..7
  const int bid  = blockIdx.x;
  const int h    = bid & 3;
  const int iblk = bid >> 2;
  const int r0   = iblk * 64;
  const int quad = lane >> 4, l16 = lane & 15;
  const float S1 = 0.4246609001f;         // sqrt((1/sqrt(64)) * log2(e))
  const f32x4 z  = {0.f,0.f,0.f,0.f};

  // ---- phase A: stage W^T into LDS (t<256) + scaled biases ----
  if (t < 256){
    const int f = t >> 2, eg = t & 3;
    {
      const float4* g = (const float4*)(Wq + h*4096 + f*64 + eg*16);
      #pragma unroll
      for (int p = 0; p < 4; ++p){
        float4 d = g[p]; int e0 = eg*16 + p*4;
        wqT[(e0+0)*72 + f] = f2bf(d.x * S1);
        wqT[(e0+1)*72 + f] = f2bf(d.y * S1);
        wqT[(e0+2)*72 + f] = f2bf(d.z * S1);
        wqT[(e0+3)*72 + f] = f2bf(d.w * S1);
      }
    }
    {
      const float4* g = (const float4*)(Wk + h*4096 + f*64 + eg*16);
      #pragma unroll
      for (int p = 0; p < 4; ++p){
        float4 d = g[p]; int e0 = eg*16 + p*4;
        wkT[(e0+0)*72 + f] = f2bf(d.x * S1);
        wkT[(e0+1)*72 + f] = f2bf(d.y * S1);
        wkT[(e0+2)*72 + f] = f2bf(d.z * S1);
        wkT[(e0+3)*72 + f] = f2bf(d.w * S1);
      }
    }
    {
      float4 d = *(const float4*)(Wv + h*1024 + f*16 + eg*4);
      int d0 = eg*4;
      wvT[(d0+0)*72 + f] = f2bf(d.x);
      wvT[(d0+1)*72 + f] = f2bf(d.y);
      wvT[(d0+2)*72 + f] = f2bf(d.z);
      wvT[(d0+3)*72 + f] = f2bf(d.w);
    }
  }
  if (t < 64)        bql[t]     = bq[h*64 + t] * S1;
  else if (t < 128)  bkl[t-64]  = bk[h*64 + (t-64)] * S1;
  else if (t < 144)  bvl[t-128] = bv[h*16 + (t-128)];
  __syncthreads();

  // ---- phase B: W fragments -> registers (waves 0-3) ----
  bf16x8 wq0 = {0,0,0,0,0,0,0,0}, wq1 = wq0, wk0 = wq0, wk1 = wq0,
         wv0 = wq0, wv1 = wq0;
  if (w < 4){
    wq0 = *(const bf16x8*)(wqT + (w*16 + l16)*72 +      quad*8);
    wq1 = *(const bf16x8*)(wqT + (w*16 + l16)*72 + 32 + quad*8);
    wk0 = *(const bf16x8*)(wkT + (w*16 + l16)*72 +      quad*8);
    wk1 = *(const bf16x8*)(wkT + (w*16 + l16)*72 + 32 + quad*8);
    wv0 = *(const bf16x8*)(wvT + l16*72 +      quad*8);
    wv1 = *(const bf16x8*)(wvT + l16*72 + 32 + quad*8);
  }
  __syncthreads();

  // ---- phase C: stage x tile -> bf16 fragment order (t<256; reuses LDS) ----
  if (t < 256){
    const int r = t >> 2, cg4 = t & 3;
    const float4* g = (const float4*)(x + (size_t)(r0 + r)*64 + cg4*16);
    float4 a = g[0], b = g[1], c = g[2], d = g[3];
    unsigned u0 = pack2bf(a.x,a.y), u1 = pack2bf(a.z,a.w);
    unsigned u2 = pack2bf(b.x,b.y), u3 = pack2bf(b.z,b.w);
    unsigned u4 = pack2bf(c.x,c.y), u5 = pack2bf(c.z,c.w);
    unsigned u6 = pack2bf(d.x,d.y), u7 = pack2bf(d.z,d.w);
    const int it = r >> 4, l16r = r & 15, ks = cg4 >> 1, q0 = (cg4 & 1)*2;
    uint4* dst0 = (uint4*)(xf + ((it*2+ks)*64 + q0*16     + l16r)*8);
    uint4* dst1 = (uint4*)(xf + ((it*2+ks)*64 + (q0+1)*16 + l16r)*8);
    *dst0 = make_uint4(u0,u1,u2,u3);
    *dst1 = make_uint4(u4,u5,u6,u7);
  }
  __syncthreads();

  // ---- phase D: projection MFMAs + epilogues (waves 0-3) ----
  if (w < 4){
    bf16x8 xa[8];
    #pragma unroll
    for (int i = 0; i < 8; ++i)
      xa[i] = *(const bf16x8*)(xf + (i*64 + lane)*8);

    f32x4 accQ[4] = {z,z,z,z};
    f32x4 accK[4] = {z,z,z,z};
    f32x4 accV = z;

    #pragma unroll
    for (int it = 0; it < 4; ++it){
      accQ[it] = __builtin_amdgcn_mfma_f32_16x16x32_bf16(wq0, xa[it*2+0], accQ[it], 0,0,0);
      accQ[it] = __builtin_amdgcn_mfma_f32_16x16x32_bf16(wq1, xa[it*2+1], accQ[it], 0,0,0);
    }
    #pragma unroll
    for (int tt = 0; tt < 4; ++tt){
      accK[tt] = __builtin_amdgcn_mfma_f32_16x16x32_bf16(wk0, xa[tt*2+0], accK[tt], 0,0,0);
      accK[tt] = __builtin_amdgcn_mfma_f32_16x16x32_bf16(wk1, xa[tt*2+1], accK[tt], 0,0,0);
    }
    accV = __builtin_amdgcn_mfma_f32_16x16x32_bf16(xa[w*2+0], wv0, accV, 0,0,0);
    accV = __builtin_amdgcn_mfma_f32_16x16x32_bf16(xa[w*2+1], wv1, accV, 0,0,0);

    // Q^T tiles -> Qfr frag bytes (block-local consumer)
    {
      const int e0 = w*16 + quad*4;
      const float b0 = bql[e0], b1 = bql[e0+1], b2 = bql[e0+2], b3 = bql[e0+3];
      const int qk = (e0 & 31) >> 3, hf = e0 >> 5, boff = (quad & 1) * 4;
      #pragma unroll
      for (int it = 0; it < 4; ++it){
        unsigned o = pack_fp8x4(accQ[it][0]+b0, accQ[it][1]+b1,
                                accQ[it][2]+b2, accQ[it][3]+b3);
        const int T = (r0 >> 4) + it;
        *(unsigned*)(Qfr + (size_t)h*((size_t)n<<6) + (size_t)T*1024
                         + (qk*16 + l16)*16 + hf*8 + boff) = o;
      }
    }
    // K^T tiles -> Kt frag bytes
    {
      const int f0 = w*16 + quad*4;
      const float bk0 = bkl[f0], bk1 = bkl[f0+1], bk2 = bkl[f0+2], bk3 = bkl[f0+3];
      const int qk = (f0 & 31) >> 3, hf = f0 >> 5, boff = (quad & 1) * 4;
      #pragma unroll
      for (int tt = 0; tt < 4; ++tt){
        unsigned o = pack_fp8x4(accK[tt][0]+bk0, accK[tt][1]+bk1,
                                accK[tt][2]+bk2, accK[tt][3]+bk3);
        const int T = (r0 >> 4) + tt;
        *(unsigned*)(Kt + (size_t)h*((size_t)n<<6) + (size_t)T*1024
                        + (qk*16 + l16)*16 + hf*8 + boff) = o;
      }
    }
    // V tile -> Vt (chunk-interleaved: 8B slot in the lane's 16B K=32 frag)
    {
      float bvv = bvl[l16];
      unsigned v01 = pack2bf(accV[0]+bvv, accV[1]+bvv);
      unsigned v23 = pack2bf(accV[2]+bvv, accV[3]+bvv);
      const int T = (r0 >> 4) + w;
      *(uint2*)(Vt + (size_t)h*((size_t)n<<4)
                   + ((size_t)(T>>1)*64 + lane)*8 + (T&1)*4) = make_uint2(v01, v23);
    }
  }

  __threadfence();
  cg::this_grid().sync();

  // ---- phase E: flash attention (verbatim R19; jq = w) ----
  const int jq = w;

  // wave phase-stagger before any memory op
  #pragma unroll 1
  for (int i = 0; i < jq; ++i) __builtin_amdgcn_s_sleep(3);

  const int i0  = r0;
  const int ntq = (n >> 3) >> 4;            // 16-key tiles per octant (64)
  const int nch = ntq >> 1;                 // 32-key chunks per octant (32)
  const int tile0 = jq * ntq;

  const unsigned char* qfh = Qfr + (size_t)h*((size_t)n<<6);
  longlong2 q0 = *(const longlong2*)(qfh + (size_t)((i0>>4)    )*1024 + lane*16);
  longlong2 q1 = *(const longlong2*)(qfh + (size_t)((i0>>4) + 1)*1024 + lane*16);
  longlong2 q2 = *(const longlong2*)(qfh + (size_t)((i0>>4) + 2)*1024 + lane*16);
  longlong2 q3 = *(const longlong2*)(qfh + (size_t)((i0>>4) + 3)*1024 + lane*16);
  const fp8x8 qf00 = (fp8x8)q0.x, qf01 = (fp8x8)q0.y;
  const fp8x8 qf10 = (fp8x8)q1.x, qf11 = (fp8x8)q1.y;
  const fp8x8 qf20 = (fp8x8)q2.x, qf21 = (fp8x8)q2.y;
  const fp8x8 qf30 = (fp8x8)q3.x, qf31 = (fp8x8)q3.y;

  const longlong2* ktl = (const longlong2*)(Kt + (size_t)h*((size_t)n<<6)) + (size_t)tile0*64 + lane;
  const uint4*     vtu = (const uint4*)(Vt + (size_t)h*((size_t)n<<4)) + (size_t)(tile0>>1)*64 + lane;

  f32x4 o0 = z, o1 = z, o2 = z, o3 = z;
  f32x4 la0 = z, la1 = z, la2 = z, la3 = z;
  const bf16x8 vones = {(short)0x3F80, (short)0x3F80, (short)0x3F80, (short)0x3F80,
                        (short)0x3F80, (short)0x3F80, (short)0x3F80, (short)0x3F80};

  longlong2 ka0 = ktl[0],   ka1 = ktl[64];
  uint4     va  = vtu[0];
  longlong2 kb0 = ktl[128], kb1 = ktl[192];
  uint4     vb  = vtu[64];

  for (int c = 0; c < nch - 2; c += 2){
    ATTN_CHUNK(ka0, ka1, va)
    ka0 = ktl[256]; ka1 = ktl[320]; va = vtu[128];
    ATTN_CHUNK(kb0, kb1, vb)
    kb0 = ktl[384]; kb1 = ktl[448]; vb = vtu[192];
    ktl += 256; vtu += 128;
    ATTN_SGB
  }
  ATTN_CHUNK(ka0, ka1, va)
  ATTN_CHUNK(kb0, kb1, vb)

  if (jq > 0){
    float* p = &part[jq-1][lane][0];
    p[ 0]=o0[0];  p[ 1]=o0[1];  p[ 2]=o0[2];  p[ 3]=o0[3];
    p[ 4]=o1[0];  p[ 5]=o1[1];  p[ 6]=o1[2];  p[ 7]=o1[3];
    p[ 8]=o2[0];  p[ 9]=o2[1];  p[10]=o2[2];  p[11]=o2[3];
    p[12]=o3[0];  p[13]=o3[1];  p[14]=o3[2];  p[15]=o3[3];
    p[16]=la0[0]; p[17]=la0[1]; p[18]=la0[2]; p[19]=la0[3];
    p[20]=la1[0]; p[21]=la1[1]; p[22]=la1[2]; p[23]=la1[3];
    p[24]=la2[0]; p[25]=la2[1]; p[26]=la2[2]; p[27]=la2[3];
    p[28]=la3[0]; p[29]=la3[1]; p[30]=la3[2]; p[31]=la3[3];
  }
  __syncthreads();

  if (jq == 0){
    #pragma unroll
    for (int q = 0; q < 7; ++q){
      const float* r = &part[q][lane][0];
      o0[0] +=r[0];  o0[1] +=r[1];  o0[2] +=r[2];  o0[3] +=r[3];
      o1[0] +=r[4];  o1[1] +=r[5];  o1[2] +=r[6];  o1[3] +=r[7];
      o2[0] +=r[8];  o2[1] +=r[9];  o2[2] +=r[10]; o2[3] +=r[11];
      o3[0] +=r[12]; o3[1] +=r[13]; o3[2] +=r[14]; o3[3] +=r[15];
      la0[0]+=r[16]; la0[1]+=r[17]; la0[2]+=r[18]; la0[3]+=r[19];
      la1[0]+=r[20]; la1[1]+=r[21]; la1[2]+=r[22]; la1[3]+=r[23];
      la2[0]+=r[24]; la2[1]+=r[25]; la2[2]+=r[26]; la2[3]+=r[27];
      la3[0]+=r[28]; la3[1]+=r[29]; la3[2]+=r[30]; la3[3]+=r[31];
    }
    #pragma unroll
    for (int reg = 0; reg < 4; ++reg){
      int i = quad*4 + reg;
      out[(size_t)(i0 +      i)*64 + h*16 + l16] = o0[reg] / la0[reg];
      out[(size_t)(i0 + 16 + i)*64 + h*16 + l16] = o1[reg] / la1[reg];
      out[(size_t)(i0 + 32 + i)*64 + h*16 + l16] = o2[reg] / la2[reg];
      out[(size_t)(i0 + 48 + i)*64 + h*16 + l16] = o3[reg] / la3[reg];
    }
  }
}

// ======================= fallback 3-kernel path ==========================
__global__ __launch_bounds__(256) void wprep_kernel(
    const float* __restrict__ Wq, const float* __restrict__ bq,
    const float* __restrict__ Wk, const float* __restrict__ bk,
    const float* __restrict__ Wv,
    unsigned short* __restrict__ WF, float* __restrict__ bias_s, int n)
{
  __shared__ unsigned short wqT[64*72];
  __shared__ unsigned short wkT[64*72];
  __shared__ unsigned short wvT[16*72];

  const int t = threadIdx.x;
  const int h = blockIdx.x;
  const float S1 = 0.4246609001f;
  const int f = t >> 2, eg = t & 3;

  {
    const float4* g = (const float4*)(Wq + h*4096 + f*64 + eg*16);
    #pragma unroll
    for (int p = 0; p < 4; ++p){
      float4 d = g[p]; int e0 = eg*16 + p*4;
      wqT[(e0+0)*72 + f] = f2bf(d.x * S1);
      wqT[(e0+1)*72 + f] = f2bf(d.y * S1);
      wqT[(e0+2)*72 + f] = f2bf(d.z * S1);
      wqT[(e0+3)*72 + f] = f2bf(d.w * S1);
    }
  }
  {
    const float4* g = (const float4*)(Wk + h*4096 + f*64 + eg*16);
    #pragma unroll
    for (int p = 0; p < 4; ++p){
      float4 d = g[p]; int e0 = eg*16 + p*4;
      wkT[(e0+0)*72 + f] = f2bf(d.x * S1);
      wkT[(e0+1)*72 + f] = f2bf(d.y * S1);
      wkT[(e0+2)*72 + f] = f2bf(d.z * S1);
      wkT[(e0+3)*72 + f] = f2bf(d.w * S1);
    }
  }
  {
    float4 d = *(const float4*)(Wv + h*1024 + f*16 + eg*4);
    int d0 = eg*4;
    wvT[(d0+0)*72 + f] = f2bf(d.x);
    wvT[(d0+1)*72 + f] = f2bf(d.y);
    wvT[(d0+2)*72 + f] = f2bf(d.z);
    wvT[(d0+3)*72 + f] = f2bf(d.w);
  }
  if (t < 64)       bias_s[h*128 + t] = bq[h*64 + t] * S1;
  else if (t < 128) bias_s[h*128 + t] = bk[h*64 + (t-64)] * S1;
  __syncthreads();

  const int lane = t & 63, w = t >> 6;
  const int quad = lane >> 4, l16 = lane & 15;
  for (int s = w; s < 18; s += 4){
    const unsigned short* src;
    if (s < 8){      int et = s>>1,     ks = s&1;     src = wqT + (et*16+l16)*72 + ks*32 + quad*8; }
    else if (s < 16){int ft = (s-8)>>1, ks = (s-8)&1; src = wkT + (ft*16+l16)*72 + ks*32 + quad*8; }
    else {           int ks = s-16;                   src = wvT + l16*72 + ks*32 + quad*8; }
    uint4 v = *(const uint4*)src;
    *(uint4*)(WF + ((size_t)(h*18 + s)*64 + lane)*8) = v;
  }
}

__global__ __launch_bounds__(256) void proj_kernel(
    const float* __restrict__ x, const float* __restrict__ bv,
    const unsigned short* __restrict__ WF, const float* __restrict__ bias_s,
    unsigned char* __restrict__ Qfr, unsigned char* __restrict__ Kt,
    unsigned short* __restrict__ Vt, int n)
{
  __shared__ unsigned short xf[8*64*8];
  __shared__ float bql[64], bkl[64], bvl[16];

  const int t  = threadIdx.x;
  const int h  = blockIdx.y;
  const int r0 = blockIdx.x * 64;

  {
    const int r = t >> 2, cg4 = t & 3;
    const float4* g = (const float4*)(x + (size_t)(r0 + r)*64 + cg4*16);
    float4 a = g[0], b = g[1], c = g[2], d = g[3];
    unsigned u0 = pack2bf(a.x,a.y), u1 = pack2bf(a.z,a.w);
    unsigned u2 = pack2bf(b.x,b.y), u3 = pack2bf(b.z,b.w);
    unsigned u4 = pack2bf(c.x,c.y), u5 = pack2bf(c.z,c.w);
    unsigned u6 = pack2bf(d.x,d.y), u7 = pack2bf(d.z,d.w);
    const int it = r >> 4, l16r = r & 15, ks = cg4 >> 1, q0 = (cg4 & 1)*2;
    uint4* dst0 = (uint4*)(xf + ((it*2+ks)*64 + q0*16     + l16r)*8);
    uint4* dst1 = (uint4*)(xf + ((it*2+ks)*64 + (q0+1)*16 + l16r)*8);
    *dst0 = make_uint4(u0,u1,u2,u3);
    *dst1 = make_uint4(u4,u5,u6,u7);
  }
  if (t < 64)        bql[t]     = bias_s[h*128 + t];
  else if (t < 128)  bkl[t-64]  = bias_s[h*128 + t];
  else if (t < 144)  bvl[t-128] = bv[h*16 + (t-128)];
  __syncthreads();

  const int lane = t & 63, w = t >> 6;
  const int quad = lane >> 4, l16 = lane & 15;

  bf16x8 xa[8];
  #pragma unroll
  for (int i = 0; i < 8; ++i)
    xa[i] = *(const bf16x8*)(xf + (i*64 + lane)*8);

  const unsigned short* WFh = WF + (size_t)h*18*64*8;
  bf16x8 wq0 = *(const bf16x8*)(WFh + ((size_t)(     w*2 + 0)*64 + lane)*8);
  bf16x8 wq1 = *(const bf16x8*)(WFh + ((size_t)(     w*2 + 1)*64 + lane)*8);
  bf16x8 wk0 = *(const bf16x8*)(WFh + ((size_t)(8  + w*2 + 0)*64 + lane)*8);
  bf16x8 wk1 = *(const bf16x8*)(WFh + ((size_t)(8  + w*2 + 1)*64 + lane)*8);
  bf16x8 wv0 = *(const bf16x8*)(WFh + ((size_t)16*64 + lane)*8);
  bf16x8 wv1 = *(const bf16x8*)(WFh + ((size_t)17*64 + lane)*8);

  const f32x4 z = {0.f,0.f,0.f,0.f};
  f32x4 accQ[4] = {z,z,z,z};
  f32x4 accK[4] = {z,z,z,z};
  f32x4 accV = z;

  #pragma unroll
  for (int it = 0; it < 4; ++it){
    accQ[it] = __builtin_amdgcn_mfma_f32_16x16x32_bf16(wq0, xa[it*2+0], accQ[it], 0,0,0);
    accQ[it] = __builtin_amdgcn_mfma_f32_16x16x32_bf16(wq1, xa[it*2+1], accQ[it], 0,0,0);
  }
  #pragma unroll
  for (int tt = 0; tt < 4; ++tt){
    accK[tt] = __builtin_amdgcn_mfma_f32_16x16x32_bf16(wk0, xa[tt*2+0], accK[tt], 0,0,0);
    accK[tt] = __builtin_amdgcn_mfma_f32_16x16x32_bf16(wk1, xa[tt*2+1], accK[tt], 0,0,0);
  }
  accV = __builtin_amdgcn_mfma_f32_16x16x32_bf16(xa[w*2+0], wv0, accV, 0,0,0);
  accV = __builtin_amdgcn_mfma_f32_16x16x32_bf16(xa[w*2+1], wv1, accV, 0,0,0);

  {
    const int e0 = w*16 + quad*4;
    const float b0 = bql[e0], b1 = bql[e0+1], b2 = bql[e0+2], b3 = bql[e0+3];
    const int qk = (e0 & 31) >> 3, hf = e0 >> 5, boff = (quad & 1) * 4;
    #pragma unroll
    for (int it = 0; it < 4; ++it){
      unsigned o = pack_fp8x4(accQ[it][0]+b0, accQ[it][1]+b1,
                              accQ[it][2]+b2, accQ[it][3]+b3);
      const int T = (r0 >> 4) + it;
      *(unsigned*)(Qfr + (size_t)h*((size_t)n<<6) + (size_t)T*1024
                       + (qk*16 + l16)*16 + hf*8 + boff) = o;
    }
  }
  {
    const int f0 = w*16 + quad*4;
    const float bk0 = bkl[f0], bk1 = bkl[f0+1], bk2 = bkl[f0+2], bk3 = bkl[f0+3];
    const int qk = (f0 & 31) >> 3, hf = f0 >> 5, boff = (quad & 1) * 4;
    #pragma unroll
    for (int tt = 0; tt < 4; ++tt){
      unsigned o = pack_fp8x4(accK[tt][0]+bk0, accK[tt][1]+bk1,
                              accK[tt][2]+bk2, accK[tt][3]+bk3);
      const int T = (r0 >> 4) + tt;
      *(unsigned*)(Kt + (size_t)h*((size_t)n<<6) + (size_t)T*1024
                      + (qk*16 + l16)*16 + hf*8 + boff) = o;
    }
  }
  {
    float bvv = bvl[l16];
    unsigned v01 = pack2bf(accV[0]+bvv, accV[1]+bvv);
    unsigned v23 = pack2bf(accV[2]+bvv, accV[3]+bvv);
    const int T = (r0 >> 4) + w;
    *(uint2*)(Vt + (size_t)h*((size_t)n<<4)
                 + ((size_t)(T>>1)*64 + lane)*8 + (T&1)*4) = make_uint2(v01, v23);
  }
}

__global__ __launch_bounds__(512, 4) void attn_kernel(
    const unsigned char* __restrict__ Qfr, const unsigned char* __restrict__ Kt,
    const unsigned short* __restrict__ Vt, float* __restrict__ out, int n)
{
  __shared__ float part[7][64][33];

  const int tid  = threadIdx.x;
  const int lane = tid & 63;
  const int jq   = tid >> 6;

  #pragma unroll 1
  for (int i = 0; i < jq; ++i) __builtin_amdgcn_s_sleep(3);

  const int bid  = blockIdx.x;
  const int h    = bid & 3;
  const int iblk = bid >> 2;
  const int l16  = lane & 15, quad = lane >> 4;
  const int i0   = iblk*64;
  const int ntq  = (n >> 3) >> 4;
  const int nch  = ntq >> 1;
  const int tile0 = jq * ntq;

  const unsigned char* qfh = Qfr + (size_t)h*((size_t)n<<6);
  longlong2 q0 = *(const longlong2*)(qfh + (size_t)((i0>>4)    )*1024 + lane*16);
  longlong2 q1 = *(const longlong2*)(qfh + (size_t)((i0>>4) + 1)*1024 + lane*16);
  longlong2 q2 = *(const longlong2*)(qfh + (size_t)((i0>>4) + 2)*1024 + lane*16);
  longlong2 q3 = *(const longlong2*)(qfh + (size_t)((i0>>4) + 3)*1024 + lane*16);
  const fp8x8 qf00 = (fp8x8)q0.x, qf01 = (fp8x8)q0.y;
  const fp8x8 qf10 = (fp8x8)q1.x, qf11 = (fp8x8)q1.y;
  const fp8x8 qf20 = (fp8x8)q2.x, qf21 = (fp8x8)q2.y;
  const fp8x8 qf30 = (fp8x8)q3.x, qf31 = (fp8x8)q3.y;

  const longlong2* ktl = (const longlong2*)(Kt + (size_t)h*((size_t)n<<6)) + (size_t)tile0*64 + lane;
  const uint4*     vtu = (const uint4*)(Vt + (size_t)h*((size_t)n<<4)) + (size_t)(tile0>>1)*64 + lane;

  const f32x4 z = {0.f,0.f,0.f,0.f};
  f32x4 o0 = z, o1 = z, o2 = z, o3 = z;
  f32x4 la0 = z, la1 = z, la2 = z, la3 = z;
  const bf16x8 vones = {(short)0x3F80, (short)0x3F80, (short)0x3F80, (short)0x3F80,
                        (short)0x3F80, (short)0x3F80, (short)0x3F80, (short)0x3F80};

  longlong2 ka0 = ktl[0],   ka1 = ktl[64];
  uint4     va  = vtu[0];
  longlong2 kb0 = ktl[128], kb1 = ktl[192];
  uint4     vb  = vtu[64];

  for (int c = 0; c < nch - 2; c += 2){
    ATTN_CHUNK(ka0, ka1, va)
    ka0 = ktl[256]; ka1 = ktl[320]; va = vtu[128];
    ATTN_CHUNK(kb0, kb1, vb)
    kb0 = ktl[384]; kb1 = ktl[448]; vb = vtu[192];
    ktl += 256; vtu += 128;
    ATTN_SGB
  }
  ATTN_CHUNK(ka0, ka1, va)
  ATTN_CHUNK(kb0, kb1, vb)

  if (jq > 0){
    float* p = &part[jq-1][lane][0];
    p[ 0]=o0[0];  p[ 1]=o0[1];  p[ 2]=o0[2];  p[ 3]=o0[3];
    p[ 4]=o1[0];  p[ 5]=o1[1];  p[ 6]=o1[2];  p[ 7]=o1[3];
    p[ 8]=o2[0];  p[ 9]=o2[1];  p[10]=o2[2];  p[11]=o2[3];
    p[12]=o3[0];  p[13]=o3[1];  p[14]=o3[2];  p[15]=o3[3];
    p[16]=la0[0]; p[17]=la0[1]; p[18]=la0[2]; p[19]=la0[3];
    p[20]=la1[0]; p[21]=la1[1]; p[22]=la1[2]; p[23]=la1[3];
    p[24]=la2[0]; p[25]=la2[1]; p[26]=la2[2]; p[27]=la2[3];
    p[28]=la3[0]; p[29]=la3[1]; p[30]=la3[2]; p[31]=la3[3];
  }
  __syncthreads();

  if (jq == 0){
    #pragma unroll
    for (int q = 0; q < 7; ++q){
      const float* r = &part[q][lane][0];
      o0[0] +=r[0];  o0[1] +=r[1];  o0[2] +=r[2];  o0[3] +=r[3];
      o1[0] +=r[4];  o1[1] +=r[5];  o1[2] +=r[6];  o1[3] +=r[7];
      o2[0] +=r[8];  o2[1] +=r[9];  o2[2] +=r[10]; o2[3] +=r[11];
      o3[0] +=r[12]; o3[1] +=r[13]; o3[2] +=r[14]; o3[3] +=r[15];
      la0[0]+=r[16]; la0[1]+=r[17]; la0[2]+=r[18]; la0[3]+=r[19];
      la1[0]+=r[20]; la1[1]+=r[21]; la1[2]+=r[22]; la1[3]+=r[23];
      la2[0]+=r[24]; la2[1]+=r[25]; la2[2]+=r[26]; la2[3]+=r[27];
      la3[0]+=r[28]; la3[1]+=r[29]; la3[2]+=r[30]; la3[3]+=r[31];
    }
    #pragma unroll
    for (int reg = 0; reg < 4; ++reg){
      int i = quad*4 + reg;
      out[(size_t)(i0 +      i)*64 + h*16 + l16] = o0[reg] / la0[reg];
      out[(size_t)(i0 + 16 + i)*64 + h*16 + l16] = o1[reg] / la1[reg];
      out[(size_t)(i0 + 32 + i)*64 + h*16 + l16] = o2[reg] / la2[reg];
      out[(size_t)(i0 + 48 + i)*64 + h*16 + l16] = o3[reg] / la3[reg];
    }
  }
}

extern "C" void kernel_launch(void* const* d_in, const int* in_sizes, int n_in,
                              void* d_out, int out_size, void* d_ws, size_t ws_size,
                              hipStream_t stream) {
  const float* x  = (const float*)d_in[0];
  const float* Wq = (const float*)d_in[1];
  const float* bq = (const float*)d_in[2];
  const float* Wk = (const float*)d_in[3];
  const float* bk = (const float*)d_in[4];
  const float* Wv = (const float*)d_in[5];
  const float* bv = (const float*)d_in[6];
  float* out = (float*)d_out;

  int n = in_sizes[0] / 64;   // 8192

  unsigned char* Qfr  = (unsigned char*)d_ws;                       // NH*n*64 B frag tiles (Q)
  unsigned char* Kt   = Qfr + (size_t)NH*n*64;                      // NH*n*64 B frag tiles (K)
  unsigned short* Vt  = (unsigned short*)(Kt + (size_t)NH*n*64);    // NH*n*16 u16 frag tiles
  unsigned short* WF  = Vt + (size_t)NH*n*16;                       // (fallback only)
  float* bias_s       = (float*)(WF + (size_t)NH*18*64*8);          // (fallback only)

  void* params[12];
  params[0]  = (void*)&x;   params[1]  = (void*)&Wq;  params[2]  = (void*)&bq;
  params[3]  = (void*)&Wk;  params[4]  = (void*)&bk;  params[5]  = (void*)&Wv;
  params[6]  = (void*)&bv;  params[7]  = (void*)&Qfr; params[8]  = (void*)&Kt;
  params[9]  = (void*)&Vt;  params[10] = (void*)&out; params[11] = (void*)&n;

  hipError_t err = hipLaunchCooperativeKernel(
      (const void*)fused_kernel, dim3((n/64)*NH), dim3(512), params, 0u, stream);

  if (err != hipSuccess){
    // fallback: proven 3-kernel path (R19 configuration)
    wprep_kernel<<<NH, 256, 0, stream>>>(Wq, bq, Wk, bk, Wv, WF, bias_s, n);
    proj_kernel<<<dim3(n/64, NH), 256, 0, stream>>>(x, bv, WF, bias_s, Qfr, Kt, Vt, n);
    attn_kernel<<<dim3((n/64)*NH), 512, 0, stream>>>(Qfr, Kt, Vt, out, n);
  }
}

// Round 9
// 118.553 us; speedup vs baseline: 2.1364x; 2.1364x over previous
//
#include <hip/hip_runtime.h>

typedef __attribute__((ext_vector_type(4))) float f32x4;
typedef __attribute__((ext_vector_type(8))) short bf16x8;
typedef long fp8x8;   // 8 packed e4m3 bytes (i64 MFMA operand)

#define NH 4

// round-to-nearest-even f32 -> bf16
static __device__ __forceinline__ unsigned short f2bf(float f){
  unsigned u = __float_as_uint(f);
  u += 0x7FFFu + ((u >> 16) & 1u);
  return (unsigned short)(u >> 16);
}

// pack two f32 -> two bf16 (round-half-up) in one uint (low = a)
static __device__ __forceinline__ unsigned pack2bf(float a, float b){
  return __builtin_amdgcn_perm(__float_as_uint(b) + 0x8000u,
                               __float_as_uint(a) + 0x8000u, 0x07060302u);
}

// pack two f32 -> two bf16 TRUNCATING (1 v_perm). Used only for P: the same
// truncated P feeds both O=P*V and l=P*1, so the truncation bias cancels.
static __device__ __forceinline__ unsigned pack2bf_t(float a, float b){
  return __builtin_amdgcn_perm(__float_as_uint(b), __float_as_uint(a), 0x07060302u);
}

// pack 4 floats into 4 fp8(e4m3) bytes of one int (byte0 = a)
static __device__ __forceinline__ int pack_fp8x4(float a, float b, float c, float d){
  int w = __builtin_amdgcn_cvt_pk_fp8_f32(a, b, 0, false);
  w     = __builtin_amdgcn_cvt_pk_fp8_f32(c, d, w, true);
  return w;
}

// ---------------- weight-prep kernel (runs once per launch, 4 blocks) ------
__global__ __launch_bounds__(256) void wprep_kernel(
    const float* __restrict__ Wq, const float* __restrict__ bq,
    const float* __restrict__ Wk, const float* __restrict__ bk,
    const float* __restrict__ Wv,
    unsigned short* __restrict__ WF, float* __restrict__ bias_s, int n)
{
  __shared__ unsigned short wqT[64*72];  // [e][f], stride 72 (16B-aligned rows)
  __shared__ unsigned short wkT[64*72];
  __shared__ unsigned short wvT[16*72];  // [d][f]

  const int t = threadIdx.x;     // 0..255
  const int h = blockIdx.x;
  const float S1 = 0.4246609001f; // sqrt((1/sqrt(64)) * log2(e))
  const int f = t >> 2, eg = t & 3;

  {
    const float4* g = (const float4*)(Wq + h*4096 + f*64 + eg*16);
    #pragma unroll
    for (int p = 0; p < 4; ++p){
      float4 d = g[p];
      int e0 = eg*16 + p*4;
      wqT[(e0+0)*72 + f] = f2bf(d.x * S1);
      wqT[(e0+1)*72 + f] = f2bf(d.y * S1);
      wqT[(e0+2)*72 + f] = f2bf(d.z * S1);
      wqT[(e0+3)*72 + f] = f2bf(d.w * S1);
    }
  }
  {
    const float4* g = (const float4*)(Wk + h*4096 + f*64 + eg*16);
    #pragma unroll
    for (int p = 0; p < 4; ++p){
      float4 d = g[p];
      int e0 = eg*16 + p*4;
      wkT[(e0+0)*72 + f] = f2bf(d.x * S1);
      wkT[(e0+1)*72 + f] = f2bf(d.y * S1);
      wkT[(e0+2)*72 + f] = f2bf(d.z * S1);
      wkT[(e0+3)*72 + f] = f2bf(d.w * S1);
    }
  }
  {
    float4 d = *(const float4*)(Wv + h*1024 + f*16 + eg*4);
    int d0 = eg*4;
    wvT[(d0+0)*72 + f] = f2bf(d.x);
    wvT[(d0+1)*72 + f] = f2bf(d.y);
    wvT[(d0+2)*72 + f] = f2bf(d.z);
    wvT[(d0+3)*72 + f] = f2bf(d.w);
  }
  if (t < 64)       bias_s[h*128 + t] = bq[h*64 + t] * S1;
  else if (t < 128) bias_s[h*128 + t] = bk[h*64 + (t-64)] * S1;
  __syncthreads();

  const int lane = t & 63, w = t >> 6;
  const int quad = lane >> 4, l16 = lane & 15;
  for (int s = w; s < 18; s += 4){
    const unsigned short* src;
    if (s < 8){      int et = s>>1,     ks = s&1;     src = wqT + (et*16+l16)*72 + ks*32 + quad*8; }
    else if (s < 16){int ft = (s-8)>>1, ks = (s-8)&1; src = wkT + (ft*16+l16)*72 + ks*32 + quad*8; }
    else {           int ks = s-16;                   src = wvT + l16*72 + ks*32 + quad*8; }
    uint4 v = *(const uint4*)src;
    *(uint4*)(WF + ((size_t)(h*18 + s)*64 + lane)*8) = v;
  }
}

// ---------------- projection kernel (MFMA) ----------------
__global__ __launch_bounds__(256) void proj_kernel(
    const float* __restrict__ x, const float* __restrict__ bv,
    const unsigned short* __restrict__ WF, const float* __restrict__ bias_s,
    unsigned char* __restrict__ Qfr, unsigned char* __restrict__ Kt,
    unsigned short* __restrict__ Vt, int n)
{
  __shared__ unsigned short xf[8*64*8];  // x frags: [it*2+ks][lane][8bf16]
  __shared__ float bql[64], bkl[64], bvl[16];

  const int t  = threadIdx.x;
  const int h  = blockIdx.y;
  const int r0 = blockIdx.x * 64;

  {
    const int r = t >> 2, cg4 = t & 3;
    const float4* g = (const float4*)(x + (size_t)(r0 + r)*64 + cg4*16);
    float4 a = g[0], b = g[1], c = g[2], d = g[3];
    unsigned u0 = pack2bf(a.x,a.y), u1 = pack2bf(a.z,a.w);
    unsigned u2 = pack2bf(b.x,b.y), u3 = pack2bf(b.z,b.w);
    unsigned u4 = pack2bf(c.x,c.y), u5 = pack2bf(c.z,c.w);
    unsigned u6 = pack2bf(d.x,d.y), u7 = pack2bf(d.z,d.w);
    const int it = r >> 4, l16r = r & 15, ks = cg4 >> 1, q0 = (cg4 & 1)*2;
    uint4* dst0 = (uint4*)(xf + ((it*2+ks)*64 + q0*16     + l16r)*8);
    uint4* dst1 = (uint4*)(xf + ((it*2+ks)*64 + (q0+1)*16 + l16r)*8);
    *dst0 = make_uint4(u0,u1,u2,u3);
    *dst1 = make_uint4(u4,u5,u6,u7);
  }
  if (t < 64)        bql[t]     = bias_s[h*128 + t];
  else if (t < 128)  bkl[t-64]  = bias_s[h*128 + t];
  else if (t < 144)  bvl[t-128] = bv[h*16 + (t-128)];
  __syncthreads();

  const int lane = t & 63, w = t >> 6;
  const int quad = lane >> 4, l16 = lane & 15;

  bf16x8 xa[8];
  #pragma unroll
  for (int i = 0; i < 8; ++i)
    xa[i] = *(const bf16x8*)(xf + (i*64 + lane)*8);

  const unsigned short* WFh = WF + (size_t)h*18*64*8;
  bf16x8 wq0 = *(const bf16x8*)(WFh + ((size_t)(     w*2 + 0)*64 + lane)*8);
  bf16x8 wq1 = *(const bf16x8*)(WFh + ((size_t)(     w*2 + 1)*64 + lane)*8);
  bf16x8 wk0 = *(const bf16x8*)(WFh + ((size_t)(8  + w*2 + 0)*64 + lane)*8);
  bf16x8 wk1 = *(const bf16x8*)(WFh + ((size_t)(8  + w*2 + 1)*64 + lane)*8);
  bf16x8 wv0 = *(const bf16x8*)(WFh + ((size_t)16*64 + lane)*8);
  bf16x8 wv1 = *(const bf16x8*)(WFh + ((size_t)17*64 + lane)*8);

  const f32x4 z = {0.f,0.f,0.f,0.f};
  f32x4 accQ[4] = {z,z,z,z};   // Q^T: rows e (tile w), cols Q-row (tile it)
  f32x4 accK[4] = {z,z,z,z};   // K^T: rows f (tile w), cols key (tile tt)
  f32x4 accV = z;

  #pragma unroll
  for (int it = 0; it < 4; ++it){
    accQ[it] = __builtin_amdgcn_mfma_f32_16x16x32_bf16(wq0, xa[it*2+0], accQ[it], 0,0,0);
    accQ[it] = __builtin_amdgcn_mfma_f32_16x16x32_bf16(wq1, xa[it*2+1], accQ[it], 0,0,0);
  }
  #pragma unroll
  for (int tt = 0; tt < 4; ++tt){
    accK[tt] = __builtin_amdgcn_mfma_f32_16x16x32_bf16(wk0, xa[tt*2+0], accK[tt], 0,0,0);
    accK[tt] = __builtin_amdgcn_mfma_f32_16x16x32_bf16(wk1, xa[tt*2+1], accK[tt], 0,0,0);
  }
  accV = __builtin_amdgcn_mfma_f32_16x16x32_bf16(xa[w*2+0], wv0, accV, 0,0,0);
  accV = __builtin_amdgcn_mfma_f32_16x16x32_bf16(xa[w*2+1], wv1, accV, 0,0,0);

  // ---- Q^T tiles -> Qfr frag bytes
  {
    const int e0 = w*16 + quad*4;
    const float b0 = bql[e0], b1 = bql[e0+1], b2 = bql[e0+2], b3 = bql[e0+3];
    const int qk = (e0 & 31) >> 3, hf = e0 >> 5, boff = (quad & 1) * 4;
    #pragma unroll
    for (int it = 0; it < 4; ++it){
      unsigned o = pack_fp8x4(accQ[it][0]+b0, accQ[it][1]+b1,
                              accQ[it][2]+b2, accQ[it][3]+b3);
      const int T = (r0 >> 4) + it;
      *(unsigned*)(Qfr + (size_t)h*((size_t)n<<6) + (size_t)T*1024
                       + (qk*16 + l16)*16 + hf*8 + boff) = o;
    }
  }
  // ---- K^T tiles -> Kt frag bytes
  {
    const int f0 = w*16 + quad*4;
    const float bk0 = bkl[f0], bk1 = bkl[f0+1], bk2 = bkl[f0+2], bk3 = bkl[f0+3];
    const int qk = (f0 & 31) >> 3, hf = f0 >> 5, boff = (quad & 1) * 4;
    #pragma unroll
    for (int tt = 0; tt < 4; ++tt){
      unsigned o = pack_fp8x4(accK[tt][0]+bk0, accK[tt][1]+bk1,
                              accK[tt][2]+bk2, accK[tt][3]+bk3);
      const int T = (r0 >> 4) + tt;
      *(unsigned*)(Kt + (size_t)h*((size_t)n<<6) + (size_t)T*1024
                      + (qk*16 + l16)*16 + hf*8 + boff) = o;
    }
  }
  // ---- V tile -> Vt (chunk-interleaved: 8B slot in the lane's 16B K=32 frag)
  {
    float bvv = bvl[l16];
    unsigned v01 = pack2bf(accV[0]+bvv, accV[1]+bvv);
    unsigned v23 = pack2bf(accV[2]+bvv, accV[3]+bvv);
    const int T = (r0 >> 4) + w;
    *(uint2*)(Vt + (size_t)h*((size_t)n<<4)
                 + ((size_t)(T>>1)*64 + lane)*8 + (T&1)*4) = make_uint2(v01, v23);
  }
}

// ---------------- flash attention kernel ----------------
// R24 = R19 revert (best verified: attn 44.4us, total 116.7) + T5 setprio.
// R23 post-mortem: cooperative fusion cost ~125us of grid-sync spin
// (MfmaUtil/VALUBusy scaled exactly by 45/172 -> phases ran full speed,
// rest was idle), AND proved the ~72-80us total-vs-kernel residual is fixed
// harness overhead: 1 kernel instead of 3 left it unchanged. Attn is the
// only attackable item. This round: the one untried overlap lever, s_setprio
// around the MFMA clusters (guide T5: +4-7% attn, m191 -- mechanism needs
// wave phase diversity, which the jq stagger provides). SGB stays at the
// R19-proven 16x{3 MFMA, 6 VALU} (R22's 12x{2,8} was a body-size miscount).
__global__ __launch_bounds__(512, 4) void attn_kernel(
    const unsigned char* __restrict__ Qfr, const unsigned char* __restrict__ Kt,
    const unsigned short* __restrict__ Vt, float* __restrict__ out, int n)
{
  __shared__ float part[7][64][33];   // 59 KB padded (33: conflict-free)

  const int tid  = threadIdx.x;
  const int lane = tid & 63;
  const int jq   = tid >> 6;     // 0..7: key-range octant

  // wave phase-stagger: ~220 cyc per jq step, before any memory op.
  #pragma unroll 1
  for (int i = 0; i < jq; ++i) __builtin_amdgcn_s_sleep(3);

  const int bid  = blockIdx.x;
  const int h    = bid & 3;
  const int iblk = bid >> 2;
  const int l16  = lane & 15, quad = lane >> 4;
  const int i0   = iblk*64;
  const int ntq  = (n >> 3) >> 4;            // 16-key tiles per octant (64)
  const int nch  = ntq >> 1;                 // 32-key chunks per octant (32)
  const int tile0 = jq * ntq;

  // Q fragments: 4 i-tiles x 2 e-halves -- DENSE (one uint4 per i-tile)
  const unsigned char* qfh = Qfr + (size_t)h*((size_t)n<<6);
  longlong2 q0 = *(const longlong2*)(qfh + (size_t)((i0>>4)    )*1024 + lane*16);
  longlong2 q1 = *(const longlong2*)(qfh + (size_t)((i0>>4) + 1)*1024 + lane*16);
  longlong2 q2 = *(const longlong2*)(qfh + (size_t)((i0>>4) + 2)*1024 + lane*16);
  longlong2 q3 = *(const longlong2*)(qfh + (size_t)((i0>>4) + 3)*1024 + lane*16);
  const fp8x8 qf00 = (fp8x8)q0.x, qf01 = (fp8x8)q0.y;
  const fp8x8 qf10 = (fp8x8)q1.x, qf11 = (fp8x8)q1.y;
  const fp8x8 qf20 = (fp8x8)q2.x, qf21 = (fp8x8)q2.y;
  const fp8x8 qf30 = (fp8x8)q3.x, qf31 = (fp8x8)q3.y;

  const longlong2* ktl = (const longlong2*)(Kt + (size_t)h*((size_t)n<<6)) + (size_t)tile0*64 + lane;
  const uint4*     vtu = (const uint4*)(Vt + (size_t)h*((size_t)n<<4)) + (size_t)(tile0>>1)*64 + lane;

  const f32x4 z = {0.f,0.f,0.f,0.f};
  f32x4 o0 = z, o1 = z, o2 = z, o3 = z;
  f32x4 la0 = z, la1 = z, la2 = z, la3 = z;
  const bf16x8 vones = {(short)0x3F80, (short)0x3F80, (short)0x3F80, (short)0x3F80,
                        (short)0x3F80, (short)0x3F80, (short)0x3F80, (short)0x3F80};

  // prologue: chunk 0 in A regs, chunk 1 in B regs
  longlong2 ka0 = ktl[0],   ka1 = ktl[64];
  uint4     va  = vtu[0];
  longlong2 kb0 = ktl[128], kb1 = ktl[192];
  uint4     vb  = vtu[64];

// one i-tile granule: 4 QK MFMAs -> 8 exp2 -> 4 packs -> 2 PV MFMAs.
// T5: setprio(1) around each MFMA cluster, setprio(0) across the exp2/pack
// stretch -- with the jq stagger, waves hit these regions at different
// times, so a wave in its MFMA burst wins issue arbitration over siblings
// doing VALU (m191 mechanism). SALU ops: no numeric or VALU-slot cost.
#define ITILE(QA, QB, OO, LL)                                                 \
  {                                                                           \
    __builtin_amdgcn_s_setprio(1);                                            \
    f32x4 s = __builtin_amdgcn_mfma_f32_16x16x32_fp8_fp8(a0, QA, z, 0,0,0);   \
    s = __builtin_amdgcn_mfma_f32_16x16x32_fp8_fp8(a1, QB, s, 0,0,0);         \
    f32x4 u = __builtin_amdgcn_mfma_f32_16x16x32_fp8_fp8(b0, QA, z, 0,0,0);   \
    u = __builtin_amdgcn_mfma_f32_16x16x32_fp8_fp8(b1, QB, u, 0,0,0);         \
    __builtin_amdgcn_s_setprio(0);                                            \
    float e0 = __builtin_amdgcn_exp2f(s[0]);                                  \
    float e1 = __builtin_amdgcn_exp2f(s[1]);                                  \
    float e2 = __builtin_amdgcn_exp2f(s[2]);                                  \
    float e3 = __builtin_amdgcn_exp2f(s[3]);                                  \
    float f0 = __builtin_amdgcn_exp2f(u[0]);                                  \
    float f1 = __builtin_amdgcn_exp2f(u[1]);                                  \
    float f2 = __builtin_amdgcn_exp2f(u[2]);                                  \
    float f3 = __builtin_amdgcn_exp2f(u[3]);                                  \
    union { uint4 uu; bf16x8 v; } pq;                                         \
    pq.uu = make_uint4(pack2bf_t(e0,e1), pack2bf_t(e2,e3),                    \
                       pack2bf_t(f0,f1), pack2bf_t(f2,f3));                   \
    __builtin_amdgcn_s_setprio(1);                                            \
    OO = __builtin_amdgcn_mfma_f32_16x16x32_bf16(pq.v, vfv,   OO, 0,0,0);     \
    LL = __builtin_amdgcn_mfma_f32_16x16x32_bf16(pq.v, vones, LL, 0,0,0);     \
    __builtin_amdgcn_s_setprio(0);                                            \
  }

#define ATTN_CHUNK(KA, KB, VV)                                                \
  {                                                                           \
    const fp8x8 a0 = (fp8x8)KA.x, a1 = (fp8x8)KA.y;                           \
    const fp8x8 b0 = (fp8x8)KB.x, b1 = (fp8x8)KB.y;                           \
    union { uint4 uu; bf16x8 v; } vfu; vfu.uu = VV;                           \
    const bf16x8 vfv = vfu.v;                                                 \
    ITILE(qf00, qf01, o0, la0)                                                \
    ITILE(qf10, qf11, o1, la1)                                                \
    ITILE(qf20, qf21, o2, la2)                                                \
    ITILE(qf30, qf31, o3, la3)                                                \
  }

  // main loop, unrolled x2: process chunk c from A regs then reload A with
  // chunk c+2; same for B with c+1/c+3. No register moves.
  for (int c = 0; c < nch - 2; c += 2){
    ATTN_CHUNK(ka0, ka1, va)
    ka0 = ktl[256]; ka1 = ktl[320]; va = vtu[128];
    ATTN_CHUNK(kb0, kb1, vb)
    kb0 = ktl[384]; kb1 = ktl[448]; vb = vtu[192];
    ktl += 256; vtu += 128;
    // R19-proven pipeline directive: 2-chunk body has 48 MFMA (24/chunk:
    // 16 QK + 4 PV + 4 la) and ~120 VALU/trans. 16x{3 MFMA, 6 VALU} = 48:96.
    #pragma unroll
    for (int g = 0; g < 16; ++g){
      __builtin_amdgcn_sched_group_barrier(0x008, 3, 0);  // 3 MFMA
      __builtin_amdgcn_sched_group_barrier(0x002, 6, 0);  // 6 VALU
    }
  }
  // tail: last two chunks, no prefetch
  ATTN_CHUNK(ka0, ka1, va)
  ATTN_CHUNK(kb0, kb1, vb)
#undef ATTN_CHUNK
#undef ITILE

  if (jq > 0){
    float* p = &part[jq-1][lane][0];
    p[ 0]=o0[0];  p[ 1]=o0[1];  p[ 2]=o0[2];  p[ 3]=o0[3];
    p[ 4]=o1[0];  p[ 5]=o1[1];  p[ 6]=o1[2];  p[ 7]=o1[3];
    p[ 8]=o2[0];  p[ 9]=o2[1];  p[10]=o2[2];  p[11]=o2[3];
    p[12]=o3[0];  p[13]=o3[1];  p[14]=o3[2];  p[15]=o3[3];
    p[16]=la0[0]; p[17]=la0[1]; p[18]=la0[2]; p[19]=la0[3];
    p[20]=la1[0]; p[21]=la1[1]; p[22]=la1[2]; p[23]=la1[3];
    p[24]=la2[0]; p[25]=la2[1]; p[26]=la2[2]; p[27]=la2[3];
    p[28]=la3[0]; p[29]=la3[1]; p[30]=la3[2]; p[31]=la3[3];
  }
  __syncthreads();

  if (jq == 0){
    #pragma unroll
    for (int q = 0; q < 7; ++q){
      const float* r = &part[q][lane][0];
      o0[0] +=r[0];  o0[1] +=r[1];  o0[2] +=r[2];  o0[3] +=r[3];
      o1[0] +=r[4];  o1[1] +=r[5];  o1[2] +=r[6];  o1[3] +=r[7];
      o2[0] +=r[8];  o2[1] +=r[9];  o2[2] +=r[10]; o2[3] +=r[11];
      o3[0] +=r[12]; o3[1] +=r[13]; o3[2] +=r[14]; o3[3] +=r[15];
      la0[0]+=r[16]; la0[1]+=r[17]; la0[2]+=r[18]; la0[3]+=r[19];
      la1[0]+=r[20]; la1[1]+=r[21]; la1[2]+=r[22]; la1[3]+=r[23];
      la2[0]+=r[24]; la2[1]+=r[25]; la2[2]+=r[26]; la2[3]+=r[27];
      la3[0]+=r[28]; la3[1]+=r[29]; la3[2]+=r[30]; la3[3]+=r[31];
    }
    #pragma unroll
    for (int reg = 0; reg < 4; ++reg){
      int i = quad*4 + reg;
      out[(size_t)(i0 +      i)*64 + h*16 + l16] = o0[reg] / la0[reg];
      out[(size_t)(i0 + 16 + i)*64 + h*16 + l16] = o1[reg] / la1[reg];
      out[(size_t)(i0 + 32 + i)*64 + h*16 + l16] = o2[reg] / la2[reg];
      out[(size_t)(i0 + 48 + i)*64 + h*16 + l16] = o3[reg] / la3[reg];
    }
  }
}

extern "C" void kernel_launch(void* const* d_in, const int* in_sizes, int n_in,
                              void* d_out, int out_size, void* d_ws, size_t ws_size,
                              hipStream_t stream) {
  const float* x  = (const float*)d_in[0];
  const float* Wq = (const float*)d_in[1];
  const float* bq = (const float*)d_in[2];
  const float* Wk = (const float*)d_in[3];
  const float* bk = (const float*)d_in[4];
  const float* Wv = (const float*)d_in[5];
  const float* bv = (const float*)d_in[6];
  float* out = (float*)d_out;

  const int n = in_sizes[0] / 64;   // 8192

  unsigned char* Qfr  = (unsigned char*)d_ws;                       // NH*n*64 B frag tiles (Q)
  unsigned char* Kt   = Qfr + (size_t)NH*n*64;                      // NH*n*64 B frag tiles (K)
  unsigned short* Vt  = (unsigned short*)(Kt + (size_t)NH*n*64);    // NH*n*16 u16 frag tiles (chunk-interleaved)
  unsigned short* WF  = Vt + (size_t)NH*n*16;                       // NH*18*64*8 u16 frags
  float* bias_s       = (float*)(WF + (size_t)NH*18*64*8);          // NH*128 f32

  wprep_kernel<<<NH, 256, 0, stream>>>(Wq, bq, Wk, bk, Wv, WF, bias_s, n);
  proj_kernel<<<dim3(n/64, NH), 256, 0, stream>>>(x, bv, WF, bias_s, Qfr, Kt, Vt, n);
  attn_kernel<<<dim3((n/64)*NH), 512, 0, stream>>>(Qfr, Kt, Vt, out, n);
}